// Round 12
// baseline (308.199 us; speedup 1.0000x reference)
//
#include <hip/hip_runtime.h>
#include <math.h>

#define Bb 256
#define Tt 1024
#define Ll 128

typedef float v2f __attribute__((ext_vector_type(2)));

// ---------------- exp(trans) transpose precompute ----------------
// expT[j*128 + i] = exp(trans[i*128 + j])
__global__ __launch_bounds__(256) void crf_expT_kernel(
    const float* __restrict__ trans, float* __restrict__ expT)
{
    int idx = blockIdx.x * 256 + threadIdx.x;   // idx = j*128 + i
    if (idx < Ll * Ll) {
        int jj = idx >> 7;
        int ii = idx & (Ll - 1);
        expT[idx] = __expf(trans[ii * Ll + jj]);
    }
}

// ---------------- numerator kernel ----------------
__global__ __launch_bounds__(256) void crf_num_kernel(
    const float* __restrict__ h, const int* __restrict__ labels,
    const float* __restrict__ mask, const float* __restrict__ trans,
    const float* __restrict__ start_trans, const float* __restrict__ end_trans,
    float* __restrict__ num_out)
{
    const int b = blockIdx.x;
    const int tid = threadIdx.x;
    const int* lab = labels + b * Tt;
    const float* mk = mask + b * Tt;
    const float* hb = h + (size_t)b * Tt * Ll;

    float acc = 0.f;
    float msum = 0.f;
    for (int t = tid; t < Tt; t += 256) {
        int lt = lab[t];
        float mt = mk[t];
        msum += mt;
        if (t < Tt - 1) {
            int lt1 = lab[t + 1];
            acc += hb[t * Ll + lt] * mt + trans[lt * Ll + lt1] * mk[t + 1];
        }
    }
    for (int off = 32; off; off >>= 1) {
        acc  += __shfl_down(acc, off, 64);
        msum += __shfl_down(msum, off, 64);
    }
    __shared__ float racc[4], rmsum[4];
    const int wave = tid >> 6;
    if ((tid & 63) == 0) { racc[wave] = acc; rmsum[wave] = msum; }
    __syncthreads();
    if (tid == 0) {
        float a = racc[0] + racc[1] + racc[2] + racc[3];
        float m = rmsum[0] + rmsum[1] + rmsum[2] + rmsum[3];
        int last_idx = (int)(m + 0.5f) - 1;
        if (last_idx < 0) last_idx = 0;
        if (last_idx > Tt - 1) last_idx = Tt - 1;
        int last_lab = lab[last_idx];
        float num = a + start_trans[lab[0]];
        num += hb[(Tt - 1) * Ll + last_lab] * mk[Tt - 1];
        num += end_trans[last_lab];
        num_out[b] = num;
    }
}

// ---------------- denominator (forward scan) kernel ----------------
// 8 WAVES (512 thr), 2 waves/SIMD: R11's 1 wave/SIMD exposed every DS-wait
// (nothing co-resident to fill the SIMD). Re-tile: colgroup = 16 contiguous
// lanes (= one DPP row) owning 4 cols; i-slice = 8 i per thread. Total MACs
// and DS lane-values invariant; per-wave VALU halves; co-wave hides DS.
//  * reduce across 16 slices: DPP xor1(0xB1), xor2(0x4E), half-mirror(0x141),
//    row-mirror(0x140) -- all within the 16-lane row = colgroup.
//  * slice stride 12 floats (48B): per-instruction bank collisions <=2-way
//    (free, m136); 16B-aligned for ds_read_b128.
//  * plain v2f mul/add (R10 form; R11's asm PKFMA added ~20cy of moves).
//  * DPP old=src (drops the zero-materialize v_mov per DPP op).
// Algebra IDENTICAL to R9-R11 (4-cadence shift update, slot refill,
// exp-domain p, e^{-16} recenter): absmax 0.0 verified three rounds.
__global__ __launch_bounds__(512)
__attribute__((amdgpu_waves_per_eu(2, 2)))
void crf_den_kernel(
    const float* __restrict__ h, const float* __restrict__ mask,
    const float* __restrict__ expT, const float* __restrict__ start_trans,
    const float* __restrict__ end_trans, const float* __restrict__ num_in,
    float* __restrict__ out)
{
    __shared__ float p_lds[2][192];      // 16 slices x 12 floats (8 data + 4 pad)
    __shared__ float mk_lds[Tt];         // staged mask row (4KB)
    __shared__ float redm[8], reds[8];

    const int b = blockIdx.x;
    const int tid = threadIdx.x;
    const int wave = tid >> 6;                     // 0..7
    const int lane = tid & 63;
    const int cg   = lane >> 4;                    // colgroup (DPP row) 0..3
    const int isl  = lane & 15;                    // i-slice 0..15 (8 i each)
    const int jbase = (wave << 4) + (cg << 2);     // 4 cols per thread
    const int wcol  = jbase + (isl & 3);           // column this lane tracks
    const bool writer = (isl < 4);
    const int waddr = (wcol >> 3) * 12 + (wcol & 7);

    const float* hb = h + (size_t)b * Tt * Ll;
    const float* mk = mask + b * Tt;

    // stage mask row into LDS, vectorized (first 256 threads x float4)
    if (tid < 256) ((float4*)mk_lds)[tid] = ((const float4*)mk)[tid];

    // E fragment: cols jbase+0..3, i in [isl*8, isl*8+8) -> 16 v2f regs
    const v2f* EAp = (const v2f*)(expT + (jbase + 0) * Ll + (isl << 3));
    const v2f* EBp = (const v2f*)(expT + (jbase + 1) * Ll + (isl << 3));
    const v2f* ECp = (const v2f*)(expT + (jbase + 2) * Ll + (isl << 3));
    const v2f* EDp = (const v2f*)(expT + (jbase + 3) * Ll + (isl << 3));
    v2f EA0=EAp[0],EA1=EAp[1],EA2=EAp[2],EA3=EAp[3];
    v2f EB0=EBp[0],EB1=EBp[1],EB2=EBp[2],EB3=EBp[3];
    v2f EC0=ECp[0],EC1=ECp[1],EC2=ECp[2],EC3=ECp[3];
    v2f ED0=EDp[0],ED1=EDp[1],ED2=EDp[2],ED3=EDp[3];

    // bootstrap t = 0: shift S0 = score_0[0] + 16, computed uniformly
    float S = start_trans[0] + hb[0] + 16.0f;
    float score0 = start_trans[wcol] + hb[wcol];
    float pw = __expf(score0 - S);
    if (writer) p_lds[0][waddr] = pw;

    // h/mask slots (slot r holds data for time t with t&3 == r)
    float h1 = hb[1 * Ll + wcol], m1 = mk[1];
    float h2 = hb[2 * Ll + wcol], m2 = mk[2];
    float h3 = hb[3 * Ll + wcol], m3 = mk[3];
    float h0 = hb[4 * Ll + wcol], m0 = mk[4];
    __syncthreads();

    float ex1 = __expf(h1) * m1, om1 = 1.f - m1;
    float ex0, om0, ex2, om2, ex3, om3;

    // DPP cross-lane add; old = src (no zero materialization needed)
#define DPPA(x, ctrl) __int_as_float(__builtin_amdgcn_update_dpp( \
        __float_as_int(x), __float_as_int(x), ctrl, 0xF, 0xF, true))

    // BODY: one scan step. RBUF = buffer read (write RBUF^1). UPD = shift
    // update step. EXc/OMc = this step's coeffs (prepared last body).
    // EXn/OMn prepared here from slot (HN,MN) for the NEXT body.
    // (HR,MR) refilled with time TR (consumed 3 bodies later; h from global
    // [vmcnt, never drained], mask from LDS broadcast [lgkm, same-step ok]).
#define BODY(RBUF, UPD, EXc, OMc, HN, MN, EXn, OMn, HR, MR, TR) {      \
    const float4* pp = (const float4*)(&p_lds[RBUF][isl * 12]);        \
    float4 Q0 = pp[0], Q1 = pp[1];                                     \
    float pz = 0.f;                                                    \
    if (UPD) pz = p_lds[RBUF][0];                                      \
    HR = hb[(TR) * Ll + wcol];                                         \
    MR = mk_lds[(TR)];                                                 \
    v2f q0 = {Q0.x,Q0.y}, q1 = {Q0.z,Q0.w};                            \
    v2f q2 = {Q1.x,Q1.y}, q3 = {Q1.z,Q1.w};                            \
    v2f A0 = q0*EA0; A0 = q1*EA1 + A0; A0 = q2*EA2 + A0; A0 = q3*EA3 + A0; \
    v2f A1 = q0*EB0; A1 = q1*EB1 + A1; A1 = q2*EB2 + A1; A1 = q3*EB3 + A1; \
    v2f A2 = q0*EC0; A2 = q1*EC1 + A2; A2 = q2*EC2 + A2; A2 = q3*EC3 + A2; \
    v2f A3 = q0*ED0; A3 = q1*ED1 + A3; A3 = q2*ED2 + A3; A3 = q3*ED3 + A3; \
    float a0 = A0.x + A0.y, a1 = A1.x + A1.y;                          \
    float a2 = A2.x + A2.y, a3 = A3.x + A3.y;                          \
    a0 += DPPA(a0,0xB1); a0 += DPPA(a0,0x4E);                          \
    a0 += DPPA(a0,0x141); a0 += DPPA(a0,0x140);                        \
    a1 += DPPA(a1,0xB1); a1 += DPPA(a1,0x4E);                          \
    a1 += DPPA(a1,0x141); a1 += DPPA(a1,0x140);                        \
    a2 += DPPA(a2,0xB1); a2 += DPPA(a2,0x4E);                          \
    a2 += DPPA(a2,0x141); a2 += DPPA(a2,0x140);                        \
    a3 += DPPA(a3,0xB1); a3 += DPPA(a3,0x4E);                          \
    a3 += DPPA(a3,0x141); a3 += DPPA(a3,0x140);                        \
    float s01 = (isl & 1) ? a1 : a0;                                   \
    float s23 = (isl & 1) ? a3 : a2;                                   \
    float acc = (isl & 2) ? s23 : s01;                                 \
    float c1 = EXc, c0 = pw * OMc;                                     \
    if (UPD) { float ed = __fdividef(1.12535175e-7f, pz);              \
               c1 *= ed; c0 *= ed; S += __logf(pz) + 16.0f; }          \
    float pn = fmaf(acc, c1, c0);                                      \
    if (writer) p_lds[(RBUF) ^ 1][waddr] = pn;                         \
    EXn = __expf(HN) * MN; OMn = 1.f - MN;                             \
    pw = pn;                                                           \
    __builtin_amdgcn_sched_barrier(0);                                 \
    asm volatile("s_waitcnt lgkmcnt(0)");                              \
    __builtin_amdgcn_s_barrier();                                      \
    __builtin_amdgcn_sched_barrier(0);                                 \
}

    // pre-loop bodies: t = 1, 2, 3 (regular; S unchanged)
    BODY(0, 0, ex1, om1, h2, m2, ex2, om2, h1, m1, 5)
    BODY(1, 0, ex2, om2, h3, m3, ex3, om3, h2, m2, 6)
    BODY(0, 0, ex3, om3, h0, m0, ex0, om0, h3, m3, 7)

    // main loop: k = 1..254, t = 4k (update), 4k+1, 4k+2, 4k+3.
    // TR = t+4 <= 1023 throughout -> no clamp arithmetic in the hot loop.
    for (int k = 1; k < 255; ++k) {
        int t4 = k << 2;
        BODY(1, 1, ex0, om0, h1, m1, ex1, om1, h0, m0, t4 + 4)
        BODY(0, 0, ex1, om1, h2, m2, ex2, om2, h1, m1, t4 + 5)
        BODY(1, 0, ex2, om2, h3, m3, ex3, om3, h2, m2, t4 + 6)
        BODY(0, 0, ex3, om3, h0, m0, ex0, om0, h3, m3, t4 + 7)
    }
    // tail k = 255: t = 1020..1023; refills are dummies (never consumed)
    BODY(1, 1, ex0, om0, h1, m1, ex1, om1, h0, m0, Tt - 1)
    BODY(0, 0, ex1, om1, h2, m2, ex2, om2, h1, m1, Tt - 1)
    BODY(1, 0, ex2, om2, h3, m3, ex3, om3, h2, m2, Tt - 1)
    BODY(0, 0, ex3, om3, h0, m0, ex0, om0, h3, m3, Tt - 1)
#undef BODY
#undef DPPA

    // ---- final logsumexp: score_j = log(p_T[j]) + S ----
    float v = __logf(pw) + S + end_trans[wcol];
    float mval = writer ? v : -1e30f;
    #pragma unroll
    for (int off = 32; off; off >>= 1) mval = fmaxf(mval, __shfl_xor(mval, off, 64));
    if (lane == 0) redm[wave] = mval;
    __syncthreads();
    float M = fmaxf(fmaxf(fmaxf(redm[0], redm[1]), fmaxf(redm[2], redm[3])),
                    fmaxf(fmaxf(redm[4], redm[5]), fmaxf(redm[6], redm[7])));
    float e = writer ? __expf(v - M) : 0.f;
    #pragma unroll
    for (int off = 32; off; off >>= 1) e += __shfl_xor(e, off, 64);
    if (lane == 0) reds[wave] = e;
    __syncthreads();
    if (tid == 0) {
        float den = M + __logf(reds[0] + reds[1] + reds[2] + reds[3] +
                               reds[4] + reds[5] + reds[6] + reds[7]);
        out[b] = num_in[b] - den;
    }
}

extern "C" void kernel_launch(void* const* d_in, const int* in_sizes, int n_in,
                              void* d_out, int out_size, void* d_ws, size_t ws_size,
                              hipStream_t stream) {
    const float* h           = (const float*)d_in[0];
    const int*   labels      = (const int*)d_in[1];
    const float* mask        = (const float*)d_in[2];
    const float* trans       = (const float*)d_in[3];
    const float* start_trans = (const float*)d_in[4];
    const float* end_trans   = (const float*)d_in[5];
    float* out    = (float*)d_out;
    float* num_ws = (float*)d_ws;                 // [0, 256)         num results
    float* expT   = (float*)d_ws + 256;           // [256, 256+16384) exp(trans)^T

    crf_expT_kernel<<<(Ll * Ll + 255) / 256, 256, 0, stream>>>(trans, expT);
    crf_num_kernel<<<Bb, 256, 0, stream>>>(h, labels, mask, trans, start_trans, end_trans, num_ws);
    crf_den_kernel<<<Bb, 512, 0, stream>>>(h, mask, expT, start_trans, end_trans, num_ws, out);
}

// Round 13
// 264.384 us; speedup vs baseline: 1.1657x; 1.1657x over previous
//
#include <hip/hip_runtime.h>
#include <math.h>

#define Bb 256
#define Tt 1024
#define Ll 128

typedef float v2f __attribute__((ext_vector_type(2)));

// ---------------- exp(trans) transpose precompute ----------------
// expT[j*128 + i] = exp(trans[i*128 + j])
__global__ __launch_bounds__(256) void crf_expT_kernel(
    const float* __restrict__ trans, float* __restrict__ expT)
{
    int idx = blockIdx.x * 256 + threadIdx.x;   // idx = j*128 + i
    if (idx < Ll * Ll) {
        int jj = idx >> 7;
        int ii = idx & (Ll - 1);
        expT[idx] = __expf(trans[ii * Ll + jj]);
    }
}

// ---------------- numerator kernel ----------------
__global__ __launch_bounds__(256) void crf_num_kernel(
    const float* __restrict__ h, const int* __restrict__ labels,
    const float* __restrict__ mask, const float* __restrict__ trans,
    const float* __restrict__ start_trans, const float* __restrict__ end_trans,
    float* __restrict__ num_out)
{
    const int b = blockIdx.x;
    const int tid = threadIdx.x;
    const int* lab = labels + b * Tt;
    const float* mk = mask + b * Tt;
    const float* hb = h + (size_t)b * Tt * Ll;

    float acc = 0.f;
    float msum = 0.f;
    for (int t = tid; t < Tt; t += 256) {
        int lt = lab[t];
        float mt = mk[t];
        msum += mt;
        if (t < Tt - 1) {
            int lt1 = lab[t + 1];
            acc += hb[t * Ll + lt] * mt + trans[lt * Ll + lt1] * mk[t + 1];
        }
    }
    for (int off = 32; off; off >>= 1) {
        acc  += __shfl_down(acc, off, 64);
        msum += __shfl_down(msum, off, 64);
    }
    __shared__ float racc[4], rmsum[4];
    const int wave = tid >> 6;
    if ((tid & 63) == 0) { racc[wave] = acc; rmsum[wave] = msum; }
    __syncthreads();
    if (tid == 0) {
        float a = racc[0] + racc[1] + racc[2] + racc[3];
        float m = rmsum[0] + rmsum[1] + rmsum[2] + rmsum[3];
        int last_idx = (int)(m + 0.5f) - 1;
        if (last_idx < 0) last_idx = 0;
        if (last_idx > Tt - 1) last_idx = Tt - 1;
        int last_lab = lab[last_idx];
        float num = a + start_trans[lab[0]];
        num += hb[(Tt - 1) * Ll + last_lab] * mk[Tt - 1];
        num += end_trans[last_lab];
        num_out[b] = num;
    }
}

// ---------------- denominator (forward scan) kernel ----------------
// R11 structure restored (4 waves/256 thr, 4 cols x 16 i per thread, padded
// p, slot-refill x4, shift update every 4th step, mask in LDS, m201 barrier).
// R12's 8-wave retile REVERTED: per-thread overhead is tiling-invariant, so
// 2 waves/SIMD doubled issue (VALU 292->465 cy/step/SIMD) for -20% per-wave.
// Two issue cuts this round (algebra identical; absmax 0.0 since R9):
//  * plain v2f mul/add (R11's asm PKFMA measured +20cy of copies vs R10)
//  * MERGED butterfly reduce: mirror level (4dpp+4add) then cndmask-merge
//    xor1/xor2 levels fold acc-selection into the butterfly: 20 instr vs 27,
//    shorter dep chain. Lane s ends holding the full sum of col jbase+(s&3).
__global__ __launch_bounds__(256)
__attribute__((amdgpu_waves_per_eu(1, 1)))
void crf_den_kernel(
    const float* __restrict__ h, const float* __restrict__ mask,
    const float* __restrict__ expT, const float* __restrict__ start_trans,
    const float* __restrict__ end_trans, const float* __restrict__ num_in,
    float* __restrict__ out)
{
    __shared__ float p_lds[2][160];      // padded: addr(i) = i + (i>>4)*4
    __shared__ float mk_lds[Tt];         // staged mask row (4KB)
    __shared__ float redm[4], reds[4];

    const int b = blockIdx.x;
    const int tid = threadIdx.x;
    const int wave = tid >> 6;
    const int lane = tid & 63;
    const int jgrp = lane >> 3;                    // 8 column-groups per wave
    const int isl  = lane & 7;                     // i-slice 0..7 (16 i each)
    const int jbase = (wave << 5) + (jgrp << 2);   // 4 columns per thread
    const int wcol  = jbase + (isl & 3);           // column this lane writes
    const bool writer = (isl < 4);
    const int waddr = wcol + ((wcol >> 4) << 2);
    const bool lb0 = (lane & 1) != 0;              // lane bit0 (acc-merge sel)
    const bool lb1 = (lane & 2) != 0;              // lane bit1

    const float* hb = h + (size_t)b * Tt * Ll;
    const float* mk = mask + b * Tt;

    // stage mask row into LDS, vectorized (256 threads x float4 = 1024)
    ((float4*)mk_lds)[tid] = ((const float4*)mk)[tid];

    // E fragment: cols jbase+0..3, i in [isl*16, isl*16+16) -> 32 v2f regs
    const v2f* EAp = (const v2f*)(expT + (jbase + 0) * Ll + (isl << 4));
    const v2f* EBp = (const v2f*)(expT + (jbase + 1) * Ll + (isl << 4));
    const v2f* ECp = (const v2f*)(expT + (jbase + 2) * Ll + (isl << 4));
    const v2f* EDp = (const v2f*)(expT + (jbase + 3) * Ll + (isl << 4));
    v2f EA0=EAp[0],EA1=EAp[1],EA2=EAp[2],EA3=EAp[3],EA4=EAp[4],EA5=EAp[5],EA6=EAp[6],EA7=EAp[7];
    v2f EB0=EBp[0],EB1=EBp[1],EB2=EBp[2],EB3=EBp[3],EB4=EBp[4],EB5=EBp[5],EB6=EBp[6],EB7=EBp[7];
    v2f EC0=ECp[0],EC1=ECp[1],EC2=ECp[2],EC3=ECp[3],EC4=ECp[4],EC5=ECp[5],EC6=ECp[6],EC7=ECp[7];
    v2f ED0=EDp[0],ED1=EDp[1],ED2=EDp[2],ED3=EDp[3],ED4=EDp[4],ED5=EDp[5],ED6=EDp[6],ED7=EDp[7];

    // bootstrap t = 0: shift S0 = score_0[0] + 16, computed uniformly
    float S = start_trans[0] + hb[0] + 16.0f;
    float score0 = start_trans[wcol] + hb[wcol];
    float pw = __expf(score0 - S);
    if (writer) p_lds[0][waddr] = pw;

    // h/mask slots (slot r holds data for time t with t&3 == r)
    float h1 = hb[1 * Ll + wcol], m1 = mk[1];
    float h2 = hb[2 * Ll + wcol], m2 = mk[2];
    float h3 = hb[3 * Ll + wcol], m3 = mk[3];
    float h0 = hb[4 * Ll + wcol], m0 = mk[4];
    __syncthreads();

    float ex1 = __expf(h1) * m1, om1 = 1.f - m1;
    float ex0, om0, ex2, om2, ex3, om3;

    // DPP cross-lane value; old=0, bound_ctrl=true (foldable to *_dpp ALU)
#define DPPA(x, ctrl) __int_as_float(__builtin_amdgcn_update_dpp( \
        0, __float_as_int(x), ctrl, 0xF, 0xF, true))

    // BODY: one scan step. RBUF = buffer read (write RBUF^1). UPD = shift
    // update step. EXc/OMc = this step's coeffs (prepared last body).
    // EXn/OMn prepared here from slot (HN,MN) for the NEXT body.
    // (HR,MR) refilled with time TR (consumed 3 bodies later; h from global
    // [vmcnt, never drained], mask from LDS broadcast [lgkm, same-step ok]).
    // Reduce: mirror(0x141) sums slice pairs (s,7-s); then xor1(0xB1) and
    // xor2(0x4E) levels MERGE accumulators via cndmask-pair: lane s ends
    // with the full 8-slice sum of acc (s&3) = col jbase+(s&3) = wcol.
#define BODY(RBUF, UPD, EXc, OMc, HN, MN, EXn, OMn, HR, MR, TR) {      \
    const float4* pp = (const float4*)(&p_lds[RBUF][isl * 20]);        \
    float4 Q0 = pp[0], Q1 = pp[1], Q2 = pp[2], Q3 = pp[3];             \
    float pz = 0.f;                                                    \
    if (UPD) pz = p_lds[RBUF][0];                                      \
    HR = hb[(TR) * Ll + wcol];                                         \
    MR = mk_lds[(TR)];                                                 \
    v2f q00 = {Q0.x,Q0.y}, q01 = {Q0.z,Q0.w};                          \
    v2f q10 = {Q1.x,Q1.y}, q11 = {Q1.z,Q1.w};                          \
    v2f q20 = {Q2.x,Q2.y}, q21 = {Q2.z,Q2.w};                          \
    v2f q30 = {Q3.x,Q3.y}, q31 = {Q3.z,Q3.w};                          \
    v2f A0 = q00*EA0; A0 = q01*EA1 + A0; A0 = q10*EA2 + A0;            \
    A0 = q11*EA3 + A0; A0 = q20*EA4 + A0; A0 = q21*EA5 + A0;           \
    A0 = q30*EA6 + A0; A0 = q31*EA7 + A0;                              \
    v2f A1 = q00*EB0; A1 = q01*EB1 + A1; A1 = q10*EB2 + A1;            \
    A1 = q11*EB3 + A1; A1 = q20*EB4 + A1; A1 = q21*EB5 + A1;           \
    A1 = q30*EB6 + A1; A1 = q31*EB7 + A1;                              \
    v2f A2 = q00*EC0; A2 = q01*EC1 + A2; A2 = q10*EC2 + A2;            \
    A2 = q11*EC3 + A2; A2 = q20*EC4 + A2; A2 = q21*EC5 + A2;           \
    A2 = q30*EC6 + A2; A2 = q31*EC7 + A2;                              \
    v2f A3 = q00*ED0; A3 = q01*ED1 + A3; A3 = q10*ED2 + A3;            \
    A3 = q11*ED3 + A3; A3 = q20*ED4 + A3; A3 = q21*ED5 + A3;           \
    A3 = q30*ED6 + A3; A3 = q31*ED7 + A3;                              \
    float a0 = A0.x + A0.y, a1 = A1.x + A1.y;                          \
    float a2 = A2.x + A2.y, a3 = A3.x + A3.y;                          \
    a0 += DPPA(a0, 0x141); a1 += DPPA(a1, 0x141);                      \
    a2 += DPPA(a2, 0x141); a3 += DPPA(a3, 0x141);                      \
    float u01 = lb0 ? a1 : a0, v01 = lb0 ? a0 : a1;                    \
    float b01 = u01 + DPPA(v01, 0xB1);                                 \
    float u23 = lb0 ? a3 : a2, v23 = lb0 ? a2 : a3;                    \
    float b23 = u23 + DPPA(v23, 0xB1);                                 \
    float uf = lb1 ? b23 : b01, vf = lb1 ? b01 : b23;                  \
    float acc = uf + DPPA(vf, 0x4E);                                   \
    float c1 = EXc, c0 = pw * OMc;                                     \
    if (UPD) { float ed = __fdividef(1.12535175e-7f, pz);              \
               c1 *= ed; c0 *= ed; S += __logf(pz) + 16.0f; }          \
    float pn = fmaf(acc, c1, c0);                                      \
    if (writer) p_lds[(RBUF) ^ 1][waddr] = pn;                         \
    EXn = __expf(HN) * MN; OMn = 1.f - MN;                             \
    pw = pn;                                                           \
    __builtin_amdgcn_sched_barrier(0);                                 \
    asm volatile("s_waitcnt lgkmcnt(0)");                              \
    __builtin_amdgcn_s_barrier();                                      \
    __builtin_amdgcn_sched_barrier(0);                                 \
}

    // pre-loop bodies: t = 1, 2, 3 (regular; S unchanged)
    BODY(0, 0, ex1, om1, h2, m2, ex2, om2, h1, m1, 5)
    BODY(1, 0, ex2, om2, h3, m3, ex3, om3, h2, m2, 6)
    BODY(0, 0, ex3, om3, h0, m0, ex0, om0, h3, m3, 7)

    // main loop: k = 1..254, t = 4k (update), 4k+1, 4k+2, 4k+3.
    // TR = t+4 <= 1023 throughout -> no clamp arithmetic in the hot loop.
    for (int k = 1; k < 255; ++k) {
        int t4 = k << 2;
        BODY(1, 1, ex0, om0, h1, m1, ex1, om1, h0, m0, t4 + 4)
        BODY(0, 0, ex1, om1, h2, m2, ex2, om2, h1, m1, t4 + 5)
        BODY(1, 0, ex2, om2, h3, m3, ex3, om3, h2, m2, t4 + 6)
        BODY(0, 0, ex3, om3, h0, m0, ex0, om0, h3, m3, t4 + 7)
    }
    // tail k = 255: t = 1020..1023; refills are dummies (never consumed)
    BODY(1, 1, ex0, om0, h1, m1, ex1, om1, h0, m0, Tt - 1)
    BODY(0, 0, ex1, om1, h2, m2, ex2, om2, h1, m1, Tt - 1)
    BODY(1, 0, ex2, om2, h3, m3, ex3, om3, h2, m2, Tt - 1)
    BODY(0, 0, ex3, om3, h0, m0, ex0, om0, h3, m3, Tt - 1)
#undef BODY
#undef DPPA

    // ---- final logsumexp: score_j = log(p_T[j]) + S ----
    float v = __logf(pw) + S + end_trans[wcol];
    float mval = writer ? v : -1e30f;
    #pragma unroll
    for (int off = 32; off; off >>= 1) mval = fmaxf(mval, __shfl_xor(mval, off, 64));
    if (lane == 0) redm[wave] = mval;
    __syncthreads();
    float M = fmaxf(fmaxf(redm[0], redm[1]), fmaxf(redm[2], redm[3]));
    float e = writer ? __expf(v - M) : 0.f;
    #pragma unroll
    for (int off = 32; off; off >>= 1) e += __shfl_xor(e, off, 64);
    if (lane == 0) reds[wave] = e;
    __syncthreads();
    if (tid == 0) {
        float den = M + __logf(reds[0] + reds[1] + reds[2] + reds[3]);
        out[b] = num_in[b] - den;
    }
}

extern "C" void kernel_launch(void* const* d_in, const int* in_sizes, int n_in,
                              void* d_out, int out_size, void* d_ws, size_t ws_size,
                              hipStream_t stream) {
    const float* h           = (const float*)d_in[0];
    const int*   labels      = (const int*)d_in[1];
    const float* mask        = (const float*)d_in[2];
    const float* trans       = (const float*)d_in[3];
    const float* start_trans = (const float*)d_in[4];
    const float* end_trans   = (const float*)d_in[5];
    float* out    = (float*)d_out;
    float* num_ws = (float*)d_ws;                 // [0, 256)         num results
    float* expT   = (float*)d_ws + 256;           // [256, 256+16384) exp(trans)^T

    crf_expT_kernel<<<(Ll * Ll + 255) / 256, 256, 0, stream>>>(trans, expT);
    crf_num_kernel<<<Bb, 256, 0, stream>>>(h, labels, mask, trans, start_trans, end_trans, num_ws);
    crf_den_kernel<<<Bb, 256, 0, stream>>>(h, mask, expT, start_trans, end_trans, num_ws, out);
}